// Round 16
// baseline (289.424 us; speedup 1.0000x reference)
//
#include <hip/hip_runtime.h>
#include <hip/hip_bf16.h>

#define H 64
#define W 128
#define P 8192        // H*W
#define DD 81
#define NS 663552     // DD*P
#define C1 96
#define C2 128
#define C3 64
#define EPSF 1e-5f
#define NSLOT 128

// LDS row strides in shorts (odd multiples of 8 shorts = odd x 16B -> even bank phases)
#define X1S 104       // 208B = 13*16B
#define X2S 136       // 272B = 17*16B
#define X1TS 136      // gram transposed tile stride

#define NGB 324       // gram blocks (x16 tiles) -- 1296x4 WORSE (r11: 4x G-atomics)
#define NGSLOT 8
// r13: k_l23 64-px tile & k_dap4 fusion both regressed; reverted.
// r14: 3-way sample split neutral. r15: XCD swizzle neutral (kept, harmless).

typedef __attribute__((ext_vector_type(8))) short bf16x8;
typedef __attribute__((ext_vector_type(4))) float f32x4;

// ---- workspace layout (floats) ----
#define S1SUM 0                                  // 128*96
#define S1SSQ (S1SUM + NSLOT * C1)               // 12288
#define M1SUM (S1SSQ + NSLOT * C1)               // 24576, 128*96
#define S3SUM (M1SUM + NSLOT * C1)               // 36864, 128*64
#define S3SSQ (S3SUM + NSLOT * C3)               // 45056
#define GSLOT (S3SSQ + NSLOT * C3)               // 53248, 8*9216
#define STATS_ZERO_FLOATS (GSLOT + NGSLOT * 9216)  // 126976
#define S1Sc 126976
#define S1Tc (S1Sc + C1)
#define S2Sc (S1Tc + C1)
#define S2Tc (S2Sc + C2)
#define S3Sc (S2Tc + C2)
#define S3Tc (S3Sc + C3)
#define COST_OFF 127552                          // 81*8192
#define FLOAT_END (COST_OFF + NS)
// byte-indexed region. aT/gT/y1T/y3T transposed: [chunk of 4ch][sample][4]
#define A_BYTE   ((size_t)FLOAT_END * 4)
#define G_BYTE   (A_BYTE + (size_t)P * 96 * 2)
#define W2BF_BYTE (G_BYTE + (size_t)P * 96 * 2)
#define W3BF_BYTE (W2BF_BYTE + (size_t)C2 * C1 * 2)
#define Y1_BYTE  (W3BF_BYTE + (size_t)C3 * C2 * 2)
#define Y3_BYTE  (Y1_BYTE + (size_t)NS * C1 * 2)
#define WS_NEEDED (Y3_BYTE + (size_t)NS * C3 * 2)

__device__ __forceinline__ float bflo(unsigned u) { return __uint_as_float(u << 16); }
__device__ __forceinline__ float bfhi(unsigned u) { return __uint_as_float(u & 0xffff0000u); }
__device__ __forceinline__ float bfu(unsigned short v) { return __uint_as_float((unsigned)v << 16); }

__device__ __forceinline__ unsigned pkbf(float a, float b) {
  __hip_bfloat162 h = __float22bfloat162_rn(make_float2(a, b));
  unsigned u; __builtin_memcpy(&u, &h, 4);
  return u;
}

// blocks 0..127: a = w1[:,:128]@f1, g = w1[:,128:]@f2 -> bf16 transposed [c4][p][4]
// blocks 128..207: convert w2/w3 to bf16 (fused k_wprep)
__global__ __launch_bounds__(256) void k_prep(const float* __restrict__ f1,
                                              const float* __restrict__ f2,
                                              const float* __restrict__ w1,
                                              unsigned short* __restrict__ aT,
                                              unsigned short* __restrict__ gT,
                                              const float* __restrict__ w2,
                                              const float* __restrict__ w3,
                                              unsigned short* __restrict__ w2bf,
                                              unsigned short* __restrict__ w3bf) {
  int t = threadIdx.x;
  if (blockIdx.x >= 128) {
    int idx = (blockIdx.x - 128) * 256 + t;
    if (idx < C2 * C1) {
      w2bf[idx] = (unsigned short)(pkbf(w2[idx], 0.f) & 0xffffu);
    } else if (idx < C2 * C1 + C3 * C2) {
      w3bf[idx - C2 * C1] = (unsigned short)(pkbf(w3[idx - C2 * C1], 0.f) & 0xffffu);
    }
    return;
  }
  __shared__ float tile[128][64];
  int p0 = blockIdx.x * 64;
  int px = t & 63, q = t >> 6;
  int c0 = q * 24;
  for (int pass = 0; pass < 2; ++pass) {
    const float* src = pass ? f2 : f1;
    unsigned short* dst = pass ? gT : aT;
    int koff = pass ? 128 : 0;
    __syncthreads();
    for (int idx = t; idx < 8192; idx += 256) {
      int kk = idx >> 6, xx = idx & 63;
      tile[kk][xx] = src[kk * P + p0 + xx];
    }
    __syncthreads();
    float acc[24];
#pragma unroll
    for (int i = 0; i < 24; ++i) acc[i] = 0.f;
    for (int kk = 0; kk < 128; ++kk) {
      float fv = tile[kk][px];
#pragma unroll
      for (int i = 0; i < 24; ++i)
        acc[i] += w1[(c0 + i) * 256 + koff + kk] * fv;
    }
#pragma unroll
    for (int i = 0; i < 24; i += 4) {
      uint2 pk;
      pk.x = pkbf(acc[i + 0], acc[i + 1]);
      pk.y = pkbf(acc[i + 2], acc[i + 3]);
      *(uint2*)(dst + ((size_t)((c0 + i) >> 2) * P + p0 + px) * 4) = pk;
    }
  }
}

// separable gather, split by x-displacement halves (r12-proven best)
__global__ __launch_bounds__(256) void k_sample(const float* __restrict__ coords,
                                                float* __restrict__ ws,
                                                const unsigned short* __restrict__ aT,
                                                const unsigned short* __restrict__ gT,
                                                unsigned short* __restrict__ y1T) {
  int t = threadIdx.x, b = blockIdx.x;
  int sub = b % 12;
  int ptile = b / 12;
  int cg = sub >> 1, jh = sub & 1;
  int j0 = jh * 5;
  int nj = 5 - jh;             // valid j count (wave-uniform)
  int c = cg * 4 + (t >> 6);   // chunk 0..23, uniform per wave
  int px = t & 63;
  int p = ptile * 64 + px;
  float cx = coords[p], cy = coords[P + p];
  float fx0 = floorf(cx), fy0 = floorf(cy);
  float wx1 = cx - fx0, wx0 = 1.f - wx1;
  float wy1 = cy - fy0, wy0 = 1.f - wy1;
  int ixb = (int)fx0 - 4 + j0, iyb = (int)fy0 - 4;
  int colOff[6];
  float vxv[6];
#pragma unroll
  for (int j = 0; j < 6; ++j) {
    int ix = ixb + j;
    vxv[j] = (ix >= 0 && ix < W) ? 1.f : 0.f;
    colOff[j] = min(max(ix, 0), W - 1);
  }
  float ewx0[5], ewx1[5];
#pragma unroll
  for (int j = 0; j < 5; ++j) { ewx0[j] = wx0 * vxv[j]; ewx1[j] = wx1 * vxv[j + 1]; }
  float av[4];
  {
    uint2 a2 = *(const uint2*)(aT + ((size_t)c * P + p) * 4);
    av[0] = bflo(a2.x); av[1] = bfhi(a2.x); av[2] = bflo(a2.y); av[3] = bfhi(a2.y);
  }
  const unsigned short* gc = gT + (size_t)c * P * 4;
  unsigned short* yb = y1T + ((size_t)c * P + p) * 4;
  float Hb[2][5][4];
  float sum[4] = {0.f, 0.f, 0.f, 0.f}, ssq[4] = {0.f, 0.f, 0.f, 0.f};
  float vyPrev = 0.f;
#pragma unroll
  for (int dy = 0; dy < 10; ++dy) {
    const int cur = dy & 1, prv = cur ^ 1;
    int iy = iyb + dy;
    float vy = (iy >= 0 && iy < H) ? 1.f : 0.f;
    const unsigned short* grow = gc + (size_t)(min(max(iy, 0), H - 1) * W) * 4;
    uint2 gv[6];
#pragma unroll
    for (int j = 0; j < 6; ++j) gv[j] = *(const uint2*)(grow + colOff[j] * 4);
#pragma unroll
    for (int j = 0; j < 5; ++j) {
      Hb[cur][j][0] = fmaf(ewx1[j], bflo(gv[j + 1].x), ewx0[j] * bflo(gv[j].x));
      Hb[cur][j][1] = fmaf(ewx1[j], bfhi(gv[j + 1].x), ewx0[j] * bfhi(gv[j].x));
      Hb[cur][j][2] = fmaf(ewx1[j], bflo(gv[j + 1].y), ewx0[j] * bflo(gv[j].y));
      Hb[cur][j][3] = fmaf(ewx1[j], bfhi(gv[j + 1].y), ewx0[j] * bfhi(gv[j].y));
    }
    if (dy >= 1) {
      const int dyk = dy - 1;
      float e0 = wy0 * vyPrev, e1 = wy1 * vy;
#pragma unroll
      for (int j = 0; j < 5; ++j) {
        if (j < nj) {   // wave-uniform guard (jh=1 has 4 valid j)
          float o0 = fmaf(e0, Hb[prv][j][0], fmaf(e1, Hb[cur][j][0], av[0]));
          float o1 = fmaf(e0, Hb[prv][j][1], fmaf(e1, Hb[cur][j][1], av[1]));
          float o2 = fmaf(e0, Hb[prv][j][2], fmaf(e1, Hb[cur][j][2], av[2]));
          float o3 = fmaf(e0, Hb[prv][j][3], fmaf(e1, Hb[cur][j][3], av[3]));
          sum[0] += o0; ssq[0] = fmaf(o0, o0, ssq[0]);
          sum[1] += o1; ssq[1] = fmaf(o1, o1, ssq[1]);
          sum[2] += o2; ssq[2] = fmaf(o2, o2, ssq[2]);
          sum[3] += o3; ssq[3] = fmaf(o3, o3, ssq[3]);
          uint2 pk;
          pk.x = pkbf(o0, o1);
          pk.y = pkbf(o2, o3);
          int kk = (j0 + j) * 9 + dyk;   // k = xdisp*9 + ydisp (reference order)
          *(uint2*)(yb + (size_t)kk * 24 * P * 4) = pk;
        }
      }
    }
    vyPrev = vy;
  }
#pragma unroll
  for (int m = 1; m < 64; m <<= 1) {
#pragma unroll
    for (int e = 0; e < 4; ++e) {
      sum[e] += __shfl_xor(sum[e], m);
      ssq[e] += __shfl_xor(ssq[e], m);
    }
  }
  if ((t & 63) == 0) {
    int slot = b & (NSLOT - 1);
#pragma unroll
    for (int e = 0; e < 4; ++e) {
      atomicAdd(&ws[S1SUM + slot * C1 + c * 4 + e], sum[e]);
      atomicAdd(&ws[S1SSQ + slot * C1 + c * 4 + e], ssq[e]);
    }
  }
}

// widened finalize: 256 threads, two slot-halves per channel, LDS combine
__global__ __launch_bounds__(256) void k_finalize(float* __restrict__ ws, int sumO, int ssqO,
                                                  const float* __restrict__ gamma,
                                                  const float* __restrict__ beta,
                                                  int sO, int tO, int C) {
  __shared__ float pss[2][128], psq[2][128];
  int t = threadIdx.x;
  int c = t & 127, half = t >> 7;
  float su = 0.f, sq = 0.f;
  if (c < C) {
    int s0 = half * 64;
    for (int s = s0; s < s0 + 64; ++s) { su += ws[sumO + s * C + c]; sq += ws[ssqO + s * C + c]; }
  }
  pss[half][c] = su; psq[half][c] = sq;
  __syncthreads();
  if (t < C) {
    su = pss[0][t] + pss[1][t];
    sq = psq[0][t] + psq[1][t];
    float mean = su * (1.0f / (float)NS);
    float var = sq * (1.0f / (float)NS) - mean * mean;
    float sc = gamma[t] * rsqrtf(var + EPSF);
    ws[sO + t] = sc;
    ws[tO + t] = beta[t] - mean * sc;
  }
}

// Gram pass: x1 = bn1+relu(y1) -> G += x1^T x1 + m1 = sum(x1); atomics into 8 G-slots
__global__ __launch_bounds__(256) void k_gram(const unsigned short* __restrict__ y1T,
                                              float* __restrict__ ws) {
  __shared__ unsigned short x1t[96 * X1TS];   // 26112B
  int t = threadIdx.x, b = blockIdx.x;
  int w = t >> 6, l = t & 63;
  int lr = l & 15, lh = l >> 4;
  int i0 = (w >> 1) * 48, j0 = (w & 1) * 48;  // each wave owns a 3x3 block of 16-tiles
  f32x4 acc[9];
  f32x4 zero4 = {0.f, 0.f, 0.f, 0.f};
#pragma unroll
  for (int q = 0; q < 9; ++q) acc[q] = zero4;
  int c = t >> 3, pg = t & 7;   // build mapping: chunk c (0..23 active), pixel group pg
  float s1v[4], t1v[4];
  if (c < 24) {
#pragma unroll
    for (int e = 0; e < 4; ++e) { s1v[e] = ws[S1Sc + c * 4 + e]; t1v[e] = ws[S1Tc + c * 4 + e]; }
  }
  float msum[4] = {0.f, 0.f, 0.f, 0.f};
  for (int it = 0; it < 16; ++it) {
    int idx = b * 16 + it;
    int k = idx >> 6, p0 = (idx & 63) << 7;
    const unsigned short* y1k = y1T + (size_t)k * P * 96;
    __syncthreads();   // previous iteration's Gram reads done
    if (c < 24) {
      int pbase = p0 + pg * 16;
      unsigned rowu[4][8];
#pragma unroll
      for (int ii = 0; ii < 8; ++ii) {
        uint4 v = *(const uint4*)(y1k + ((size_t)c * P + pbase + ii * 2) * 4);
        float x00 = fmaxf(0.f, fmaf(s1v[0], bflo(v.x), t1v[0]));
        float x10 = fmaxf(0.f, fmaf(s1v[1], bfhi(v.x), t1v[1]));
        float x20 = fmaxf(0.f, fmaf(s1v[2], bflo(v.y), t1v[2]));
        float x30 = fmaxf(0.f, fmaf(s1v[3], bfhi(v.y), t1v[3]));
        float x01 = fmaxf(0.f, fmaf(s1v[0], bflo(v.z), t1v[0]));
        float x11 = fmaxf(0.f, fmaf(s1v[1], bfhi(v.z), t1v[1]));
        float x21 = fmaxf(0.f, fmaf(s1v[2], bflo(v.w), t1v[2]));
        float x31 = fmaxf(0.f, fmaf(s1v[3], bfhi(v.w), t1v[3]));
        msum[0] += x00 + x01; msum[1] += x10 + x11;
        msum[2] += x20 + x21; msum[3] += x30 + x31;
        rowu[0][ii] = pkbf(x00, x01);
        rowu[1][ii] = pkbf(x10, x11);
        rowu[2][ii] = pkbf(x20, x21);
        rowu[3][ii] = pkbf(x30, x31);
      }
#pragma unroll
      for (int e = 0; e < 4; ++e) {
        unsigned short* dst = x1t + (c * 4 + e) * X1TS + pg * 16;
        uint4 pk0; pk0.x = rowu[e][0]; pk0.y = rowu[e][1]; pk0.z = rowu[e][2]; pk0.w = rowu[e][3];
        uint4 pk1; pk1.x = rowu[e][4]; pk1.y = rowu[e][5]; pk1.z = rowu[e][6]; pk1.w = rowu[e][7];
        *(uint4*)dst = pk0;
        *(uint4*)(dst + 8) = pk1;
      }
    }
    __syncthreads();
#pragma unroll
    for (int kk = 0; kk < 4; ++kk) {
      bf16x8 a3[3], b3[3];
#pragma unroll
      for (int a = 0; a < 3; ++a)
        a3[a] = *(const bf16x8*)(const void*)(x1t + (i0 + a * 16 + lr) * X1TS + kk * 32 + lh * 8);
#pragma unroll
      for (int bb = 0; bb < 3; ++bb)
        b3[bb] = *(const bf16x8*)(const void*)(x1t + (j0 + bb * 16 + lr) * X1TS + kk * 32 + lh * 8);
#pragma unroll
      for (int a = 0; a < 3; ++a)
#pragma unroll
        for (int bb = 0; bb < 3; ++bb)
          acc[a * 3 + bb] = __builtin_amdgcn_mfma_f32_16x16x32_bf16(a3[a], b3[bb], acc[a * 3 + bb], 0, 0, 0);
    }
  }
  // accumulate partial G into L2-resident slot copies
  {
    float* gp = ws + GSLOT + (b & (NGSLOT - 1)) * 9216;
#pragma unroll
    for (int a = 0; a < 3; ++a)
#pragma unroll
      for (int bb = 0; bb < 3; ++bb) {
        int ti = (w >> 1) * 3 + a, tj = (w & 1) * 3 + bb;
        f32x4 v = acc[a * 3 + bb];
#pragma unroll
        for (int r = 0; r < 4; ++r)
          atomicAdd(&gp[(ti * 16 + lh * 4 + r) * 96 + tj * 16 + lr], v[r]);
      }
  }
  if (c < 24) {
#pragma unroll
    for (int m = 1; m < 8; m <<= 1)
#pragma unroll
      for (int e = 0; e < 4; ++e) msum[e] += __shfl_xor(msum[e], m);
    if (pg == 0) {
      int slot = b & (NSLOT - 1);
#pragma unroll
      for (int e = 0; e < 4; ++e) atomicAdd(&ws[M1SUM + slot * C1 + c * 4 + e], msum[e]);
    }
  }
}

// stats2 from Gram: reads the 8 G-slots directly (k_greduce eliminated)
__global__ __launch_bounds__(256) void k_fin2g(float* __restrict__ ws,
                                               const unsigned short* __restrict__ w2bf,
                                               const float* __restrict__ g2,
                                               const float* __restrict__ be2) {
  __shared__ float wrow[96];
  __shared__ float m1f[96];
  __shared__ float red[8];
  int o = blockIdx.x, t = threadIdx.x;
  if (t < 96) {
    wrow[t] = bfu(w2bf[o * 96 + t]);
    float s = 0.f;
    for (int sl = 0; sl < NSLOT; ++sl) s += ws[M1SUM + sl * C1 + t];
    m1f[t] = s;
  }
  __syncthreads();
  float quad = 0.f;
  for (int e = t; e < 9216; e += 256) {
    int i = e / 96, j = e - i * 96;
    float gs = 0.f;
#pragma unroll
    for (int g = 0; g < NGSLOT; ++g) gs += ws[GSLOT + g * 9216 + e];
    quad = fmaf(wrow[i] * wrow[j], gs, quad);
  }
  float msm = (t < 96) ? wrow[t] * m1f[t] : 0.f;
#pragma unroll
  for (int m = 1; m < 64; m <<= 1) { quad += __shfl_xor(quad, m); msm += __shfl_xor(msm, m); }
  if ((t & 63) == 0) { red[t >> 6] = quad; red[4 + (t >> 6)] = msm; }
  __syncthreads();
  if (t == 0) {
    float q = red[0] + red[1] + red[2] + red[3];
    float mm = red[4] + red[5] + red[6] + red[7];
    float mean = mm * (1.0f / (float)NS);
    float var = q * (1.0f / (float)NS) - mean * mean;
    float sc = g2[o] * rsqrtf(var + EPSF);
    ws[S2Sc + o] = sc;
    ws[S2Tc + o] = be2[o] - mean * sc;
  }
}

// build x1 (bn1+relu of y1T) into [128][X1S] LDS tile; y1k = k-plane base
__device__ __forceinline__ void build_x1(const unsigned short* __restrict__ y1k,
                                         const float* __restrict__ ws,
                                         unsigned short* lds, int p0, int t) {
  int s = t >> 1, hh = t & 1;
  int p = p0 + s;
  const float* s1p = ws + S1Sc;
  const float* t1p = ws + S1Tc;
  unsigned short* base = lds + s * X1S + hh * 48;
#pragma unroll
  for (int i2 = 0; i2 < 6; ++i2) {
    int c0 = hh * 12 + i2 * 2;
    uint2 va = *(const uint2*)(y1k + ((size_t)c0 * P + p) * 4);
    uint2 vb = *(const uint2*)(y1k + ((size_t)(c0 + 1) * P + p) * 4);
    int cb = c0 * 4;
    float x0 = fmaxf(0.f, fmaf(s1p[cb + 0], bflo(va.x), t1p[cb + 0]));
    float x1 = fmaxf(0.f, fmaf(s1p[cb + 1], bfhi(va.x), t1p[cb + 1]));
    float x2 = fmaxf(0.f, fmaf(s1p[cb + 2], bflo(va.y), t1p[cb + 2]));
    float x3 = fmaxf(0.f, fmaf(s1p[cb + 3], bfhi(va.y), t1p[cb + 3]));
    float x4 = fmaxf(0.f, fmaf(s1p[cb + 4], bflo(vb.x), t1p[cb + 4]));
    float x5 = fmaxf(0.f, fmaf(s1p[cb + 5], bfhi(vb.x), t1p[cb + 5]));
    float x6 = fmaxf(0.f, fmaf(s1p[cb + 6], bflo(vb.y), t1p[cb + 6]));
    float x7 = fmaxf(0.f, fmaf(s1p[cb + 7], bfhi(vb.y), t1p[cb + 7]));
    uint4 pk;
    pk.x = pkbf(x0, x1); pk.y = pkbf(x2, x3); pk.z = pkbf(x4, x5); pk.w = pkbf(x6, x7);
    *(uint4*)(base + i2 * 8) = pk;
  }
}

// fused layers 2+3 (128-px blocks); XCD-swizzled block order
__global__ __launch_bounds__(256) void k_l23(const unsigned short* __restrict__ y1T,
                                             float* __restrict__ ws,
                                             const unsigned short* __restrict__ w2bf,
                                             const unsigned short* __restrict__ w3bf,
                                             unsigned short* __restrict__ y3T) {
  __shared__ unsigned short ldss[128 * X1S];
  int t = threadIdx.x;
  int b = (blockIdx.x & 7) * 648 + (blockIdx.x >> 3);
  int k = b >> 6, p0 = (b & 63) << 7;
  size_t n0 = (size_t)k * P + p0;
  int slot = b & (NSLOT - 1);
  const unsigned short* y1k = y1T + (size_t)k * P * 96;
  build_x1(y1k, ws, ldss, p0, t);
  __syncthreads();
  int l = t & 63, wv = t >> 6;
  int o0w = wv * 32;
  int lr = l & 15, lh = l >> 4;
  bf16x8 af[2][3];
#pragma unroll
  for (int m = 0; m < 2; ++m)
#pragma unroll
    for (int kk = 0; kk < 3; ++kk)
      af[m][kk] = *(const bf16x8*)(const void*)(w2bf + (size_t)(o0w + m * 16 + lr) * 96 + kk * 32 + lh * 8);
  f32x4 acc[2][8];
  f32x4 zero4 = {0.f, 0.f, 0.f, 0.f};
#pragma unroll
  for (int m = 0; m < 2; ++m)
#pragma unroll
    for (int n = 0; n < 8; ++n) acc[m][n] = zero4;
#pragma unroll
  for (int kk = 0; kk < 3; ++kk)
#pragma unroll
    for (int n = 0; n < 8; ++n) {
      bf16x8 bfr = *(const bf16x8*)(const void*)(ldss + (n * 16 + lr) * X1S + kk * 32 + lh * 8);
      acc[0][n] = __builtin_amdgcn_mfma_f32_16x16x32_bf16(af[0][kk], bfr, acc[0][n], 0, 0, 0);
      acc[1][n] = __builtin_amdgcn_mfma_f32_16x16x32_bf16(af[1][kk], bfr, acc[1][n], 0, 0, 0);
    }
  float s2v[2][4], t2v[2][4];
#pragma unroll
  for (int m = 0; m < 2; ++m)
#pragma unroll
    for (int r = 0; r < 4; ++r) {
      int cc = o0w + m * 16 + lh * 4 + r;
      s2v[m][r] = ws[S2Sc + cc];
      t2v[m][r] = ws[S2Tc + cc];
    }
  int o2 = wv * 16;
  int ch4 = wv * 4 + lh;   // y3T chunk this lane writes
  bf16x8 af2[4];
#pragma unroll
  for (int kk = 0; kk < 4; ++kk)
    af2[kk] = *(const bf16x8*)(const void*)(w3bf + (size_t)(o2 + lr) * 128 + kk * 32 + lh * 8);
  unsigned short* x2s = ldss;               // [64][X2S] = 17408B (aliases x1)
  float ssum[4] = {0.f, 0.f, 0.f, 0.f}, sssq[4] = {0.f, 0.f, 0.f, 0.f};
#pragma unroll
  for (int h = 0; h < 2; ++h) {
    __syncthreads();   // h0: MFMA1 x1-reads done; h1: MFMA2(h0) x2-reads done
#pragma unroll
    for (int m = 0; m < 2; ++m)
#pragma unroll
      for (int n2 = 0; n2 < 4; ++n2) {
        f32x4 v = acc[m][h * 4 + n2];
        float x0 = fmaxf(0.f, fmaf(s2v[m][0], v[0], t2v[m][0]));
        float x1v = fmaxf(0.f, fmaf(s2v[m][1], v[1], t2v[m][1]));
        float x2v = fmaxf(0.f, fmaf(s2v[m][2], v[2], t2v[m][2]));
        float x3 = fmaxf(0.f, fmaf(s2v[m][3], v[3], t2v[m][3]));
        uint2 pk;
        pk.x = pkbf(x0, x1v);
        pk.y = pkbf(x2v, x3);
        *(uint2*)(x2s + (n2 * 16 + lr) * X2S + o0w + m * 16 + lh * 4) = pk;
      }
    __syncthreads();
    f32x4 acc2[4];
#pragma unroll
    for (int n2 = 0; n2 < 4; ++n2) acc2[n2] = zero4;
#pragma unroll
    for (int kk = 0; kk < 4; ++kk)
#pragma unroll
      for (int n2 = 0; n2 < 4; ++n2) {
        bf16x8 bfr = *(const bf16x8*)(const void*)(x2s + (n2 * 16 + lr) * X2S + kk * 32 + lh * 8);
        acc2[n2] = __builtin_amdgcn_mfma_f32_16x16x32_bf16(af2[kk], bfr, acc2[n2], 0, 0, 0);
      }
    // stats3 + direct transposed store
#pragma unroll
    for (int n2 = 0; n2 < 4; ++n2) {
      f32x4 v = acc2[n2];
#pragma unroll
      for (int r = 0; r < 4; ++r) { float x = v[r]; ssum[r] += x; sssq[r] = fmaf(x, x, sssq[r]); }
      uint2 pk;
      pk.x = pkbf(v[0], v[1]);
      pk.y = pkbf(v[2], v[3]);
      size_t n = n0 + h * 64 + n2 * 16 + lr;
      *(uint2*)(y3T + ((size_t)ch4 * NS + n) * 4) = pk;
    }
  }
#pragma unroll
  for (int msk = 1; msk < 16; msk <<= 1)
#pragma unroll
    for (int i = 0; i < 4; ++i) { ssum[i] += __shfl_xor(ssum[i], msk); sssq[i] += __shfl_xor(sssq[i], msk); }
  if (lr == 0) {
#pragma unroll
    for (int r = 0; r < 4; ++r) {
      int o = o2 + lh * 4 + r;
      atomicAdd(&ws[S3SUM + slot * C3 + o], ssum[r]);
      atomicAdd(&ws[S3SSQ + slot * C3 + o], sssq[r]);
    }
  }
}

// layer4: cost = w4 . relu(bn3(y3T)) + b4
__global__ __launch_bounds__(256) void k_layer4(const unsigned short* __restrict__ y3T,
                                                float* __restrict__ ws,
                                                const float* __restrict__ w4,
                                                const float* __restrict__ b4) {
  size_t n = (size_t)blockIdx.x * 256 + threadIdx.x;
  const float* s3p = ws + S3Sc;
  const float* t3p = ws + S3Tc;
  float acc = 0.f;
#pragma unroll
  for (int c16 = 0; c16 < 16; ++c16) {
    uint2 v = *(const uint2*)(y3T + ((size_t)c16 * NS + n) * 4);
    int c = c16 * 4;
    acc += fmaxf(0.f, fmaf(s3p[c + 0], bflo(v.x), t3p[c + 0])) * w4[c + 0];
    acc += fmaxf(0.f, fmaf(s3p[c + 1], bfhi(v.x), t3p[c + 1])) * w4[c + 1];
    acc += fmaxf(0.f, fmaf(s3p[c + 2], bflo(v.y), t3p[c + 2])) * w4[c + 2];
    acc += fmaxf(0.f, fmaf(s3p[c + 3], bfhi(v.y), t3p[c + 3])) * w4[c + 3];
  }
  ws[COST_OFF + n] = acc + b4[0];
}

// DAP
__global__ __launch_bounds__(256) void k_dap(const float* __restrict__ ws,
                                             const float* __restrict__ wdap,
                                             float* __restrict__ out) {
  __shared__ float wd[DD * DD];
  int t = threadIdx.x;
  for (int i = t; i < DD * DD; i += 256) wd[i] = wdap[i];
  __syncthreads();
  int p = blockIdx.x * 32 + (t & 31);
  int lg = t >> 5;
  const float* cost = ws + COST_OFF;
  float cr[81];
#pragma unroll
  for (int kk = 0; kk < 81; ++kk) cr[kk] = cost[kk * P + p];
  for (int l = lg; l < 81; l += 8) {
    float acc = 0.f;
#pragma unroll
    for (int kk = 0; kk < 81; ++kk) acc = fmaf(wd[l * 81 + kk], cr[kk], acc);
    out[(size_t)l * P + p] = acc;
  }
}

__global__ void k_marker(float* out) { out[0] = 1.0e30f; }

extern "C" void kernel_launch(void* const* d_in, const int* in_sizes, int n_in,
                              void* d_out, int out_size, void* d_ws, size_t ws_size,
                              hipStream_t stream) {
  const float* f1 = (const float*)d_in[0];
  const float* f2 = (const float*)d_in[1];
  const float* coords = (const float*)d_in[2];
  const float* w1 = (const float*)d_in[3];
  const float* g1 = (const float*)d_in[4];
  const float* be1 = (const float*)d_in[5];
  const float* w2 = (const float*)d_in[6];
  const float* g2 = (const float*)d_in[7];
  const float* be2 = (const float*)d_in[8];
  const float* w3 = (const float*)d_in[9];
  const float* g3 = (const float*)d_in[10];
  const float* be3 = (const float*)d_in[11];
  const float* w4 = (const float*)d_in[12];
  const float* b4 = (const float*)d_in[13];
  const float* wdap = (const float*)d_in[14];
  float* out = (float*)d_out;
  float* ws = (float*)d_ws;

  if (ws_size < WS_NEEDED) {
    k_marker<<<1, 1, 0, stream>>>(out);
    return;
  }
  unsigned short* aT = (unsigned short*)((char*)d_ws + A_BYTE);
  unsigned short* gT = (unsigned short*)((char*)d_ws + G_BYTE);
  unsigned short* w2bf = (unsigned short*)((char*)d_ws + W2BF_BYTE);
  unsigned short* w3bf = (unsigned short*)((char*)d_ws + W3BF_BYTE);
  unsigned short* y1T = (unsigned short*)((char*)d_ws + Y1_BYTE);
  unsigned short* y3T = (unsigned short*)((char*)d_ws + Y3_BYTE);

  hipMemsetAsync(d_ws, 0, (size_t)STATS_ZERO_FLOATS * 4, stream);
  k_prep<<<208, 256, 0, stream>>>(f1, f2, w1, aT, gT, w2, w3, w2bf, w3bf);
  k_sample<<<1536, 256, 0, stream>>>(coords, ws, aT, gT, y1T);
  k_finalize<<<1, 256, 0, stream>>>(ws, S1SUM, S1SSQ, g1, be1, S1Sc, S1Tc, C1);
  k_gram<<<NGB, 256, 0, stream>>>(y1T, ws);
  k_fin2g<<<128, 256, 0, stream>>>(ws, w2bf, g2, be2);
  k_l23<<<5184, 256, 0, stream>>>(y1T, ws, w2bf, w3bf, y3T);
  k_finalize<<<1, 256, 0, stream>>>(ws, S3SUM, S3SSQ, g3, be3, S3Sc, S3Tc, C3);
  k_layer4<<<2592, 256, 0, stream>>>(y3T, ws, w4, b4);
  k_dap<<<256, 256, 0, stream>>>(ws, wdap, out);
}

// Round 17
// 289.029 us; speedup vs baseline: 1.0014x; 1.0014x over previous
//
#include <hip/hip_runtime.h>
#include <hip/hip_bf16.h>

#define H 64
#define W 128
#define P 8192        // H*W
#define DD 81
#define NS 663552     // DD*P
#define C1 96
#define C2 128
#define C3 64
#define EPSF 1e-5f
#define NSLOT 128

// LDS row strides in shorts (odd multiples of 8 shorts = odd x 16B -> even bank phases)
#define X1S 104       // 208B = 13*16B
#define X2S 136       // 272B = 17*16B
#define X1TS 136      // gram transposed tile stride

#define NGB 324       // gram blocks (x16 tiles) -- 1296x4 WORSE (r11: 4x G-atomics)
#define NGSLOT 8
// r13: l23 64-px tile & dap4 fusion regressed. r14: 3-way 4ch split neutral.
// r15: XCD swizzle neutral (kept). r16: launch consolidation slightly negative (reverted).
// r17: y1/g/a layout [c8][p][8] -> all k_sample traffic is 16B/request (L2-request-rate bound fix).

typedef __attribute__((ext_vector_type(8))) short bf16x8;
typedef __attribute__((ext_vector_type(4))) float f32x4;

// ---- workspace layout (floats) ----
#define S1SUM 0                                  // 128*96
#define S1SSQ (S1SUM + NSLOT * C1)               // 12288
#define M1SUM (S1SSQ + NSLOT * C1)               // 24576, 128*96
#define S3SUM (M1SUM + NSLOT * C1)               // 36864, 128*64
#define S3SSQ (S3SUM + NSLOT * C3)               // 45056
#define GSLOT (S3SSQ + NSLOT * C3)               // 53248, 8*9216
#define STATS_ZERO_FLOATS (GSLOT + NGSLOT * 9216)  // 126976
#define S1Sc 126976
#define S1Tc (S1Sc + C1)
#define S2Sc (S1Tc + C1)
#define S2Tc (S2Sc + C2)
#define S3Sc (S2Tc + C2)
#define S3Tc (S3Sc + C3)
#define GOFF 127552                              // 9216 reduced Gram
#define COST_OFF (GOFF + 9216)                   // 136768
#define FLOAT_END (COST_OFF + NS)                // 800320
// byte-indexed region. aT/gT: [c8 chunk(12)][pixel][8]; y1T: [k][c8(12)][pixel][8]; y3T: [c4][n][4]
#define A_BYTE   ((size_t)FLOAT_END * 4)
#define G_BYTE   (A_BYTE + (size_t)P * 96 * 2)
#define W2BF_BYTE (G_BYTE + (size_t)P * 96 * 2)
#define W3BF_BYTE (W2BF_BYTE + (size_t)C2 * C1 * 2)
#define Y1_BYTE  (W3BF_BYTE + (size_t)C3 * C2 * 2)
#define Y3_BYTE  (Y1_BYTE + (size_t)NS * C1 * 2)
#define WS_NEEDED (Y3_BYTE + (size_t)NS * C3 * 2)

__device__ __forceinline__ float bflo(unsigned u) { return __uint_as_float(u << 16); }
__device__ __forceinline__ float bfhi(unsigned u) { return __uint_as_float(u & 0xffff0000u); }
__device__ __forceinline__ float bfu(unsigned short v) { return __uint_as_float((unsigned)v << 16); }

__device__ __forceinline__ unsigned pkbf(float a, float b) {
  __hip_bfloat162 h = __float22bfloat162_rn(make_float2(a, b));
  unsigned u; __builtin_memcpy(&u, &h, 4);
  return u;
}

// a = w1[:, :128] @ f1, g = w1[:, 128:] @ f2  -> bf16, transposed [c8][p][8]
__global__ __launch_bounds__(256) void k_prep(const float* __restrict__ f1,
                                              const float* __restrict__ f2,
                                              const float* __restrict__ w1,
                                              unsigned short* __restrict__ aT,
                                              unsigned short* __restrict__ gT) {
  __shared__ float tile[128][64];
  int t = threadIdx.x;
  int p0 = blockIdx.x * 64;
  int px = t & 63, q = t >> 6;
  int c0 = q * 24;
  for (int pass = 0; pass < 2; ++pass) {
    const float* src = pass ? f2 : f1;
    unsigned short* dst = pass ? gT : aT;
    int koff = pass ? 128 : 0;
    __syncthreads();
    for (int idx = t; idx < 8192; idx += 256) {
      int kk = idx >> 6, xx = idx & 63;
      tile[kk][xx] = src[kk * P + p0 + xx];
    }
    __syncthreads();
    float acc[24];
#pragma unroll
    for (int i = 0; i < 24; ++i) acc[i] = 0.f;
    for (int kk = 0; kk < 128; ++kk) {
      float fv = tile[kk][px];
#pragma unroll
      for (int i = 0; i < 24; ++i)
        acc[i] += w1[(c0 + i) * 256 + koff + kk] * fv;
    }
#pragma unroll
    for (int i = 0; i < 24; i += 8) {
      uint4 pk;
      pk.x = pkbf(acc[i + 0], acc[i + 1]);
      pk.y = pkbf(acc[i + 2], acc[i + 3]);
      pk.z = pkbf(acc[i + 4], acc[i + 5]);
      pk.w = pkbf(acc[i + 6], acc[i + 7]);
      *(uint4*)(dst + ((size_t)((c0 + i) >> 3) * P + p0 + px) * 8) = pk;
    }
  }
}

__global__ void k_wprep(const float* __restrict__ w2, const float* __restrict__ w3,
                        unsigned short* __restrict__ w2bf, unsigned short* __restrict__ w3bf) {
  int idx = blockIdx.x * 256 + threadIdx.x;
  if (idx < C2 * C1) {
    w2bf[idx] = (unsigned short)(pkbf(w2[idx], 0.f) & 0xffffu);
  } else if (idx < C2 * C1 + C3 * C2) {
    w3bf[idx - C2 * C1] = (unsigned short)(pkbf(w3[idx - C2 * C1], 0.f) & 0xffffu);
  }
}

// separable gather, 8 channels/thread, 16B loads/stores; 3-way x-displacement split
// block = (ptile(128), jt(3), cw(3)); wave handles c8 = cw*4 + waveid
__global__ __launch_bounds__(256) void k_sample(const float* __restrict__ coords,
                                                float* __restrict__ ws,
                                                const unsigned short* __restrict__ aT,
                                                const unsigned short* __restrict__ gT,
                                                unsigned short* __restrict__ y1T) {
  int t = threadIdx.x, b = blockIdx.x;
  int sub = b % 9;
  int ptile = b / 9;
  int jt = sub / 3, cw = sub % 3;
  int j0 = jt * 3;
  int c8 = cw * 4 + (t >> 6);   // 0..11, uniform per wave
  int px = t & 63;
  int p = ptile * 64 + px;
  float cx = coords[p], cy = coords[P + p];
  float fx0 = floorf(cx), fy0 = floorf(cy);
  float wx1 = cx - fx0, wx0 = 1.f - wx1;
  float wy1 = cy - fy0, wy0 = 1.f - wy1;
  int ixb = (int)fx0 - 4 + j0, iyb = (int)fy0 - 4;
  int colOff[4];
  float vxv[4];
#pragma unroll
  for (int j = 0; j < 4; ++j) {
    int ix = ixb + j;
    vxv[j] = (ix >= 0 && ix < W) ? 1.f : 0.f;
    colOff[j] = min(max(ix, 0), W - 1);
  }
  float ewx0[3], ewx1[3];
#pragma unroll
  for (int j = 0; j < 3; ++j) { ewx0[j] = wx0 * vxv[j]; ewx1[j] = wx1 * vxv[j + 1]; }
  float av[8];
  {
    uint4 a4 = *(const uint4*)(aT + ((size_t)c8 * P + p) * 8);
    av[0] = bflo(a4.x); av[1] = bfhi(a4.x); av[2] = bflo(a4.y); av[3] = bfhi(a4.y);
    av[4] = bflo(a4.z); av[5] = bfhi(a4.z); av[6] = bflo(a4.w); av[7] = bfhi(a4.w);
  }
  const unsigned short* gc = gT + (size_t)c8 * P * 8;
  unsigned short* yb = y1T + ((size_t)c8 * P + p) * 8;
  float Hb[2][3][8];
  float sum[8] = {0.f, 0.f, 0.f, 0.f, 0.f, 0.f, 0.f, 0.f};
  float ssq[8] = {0.f, 0.f, 0.f, 0.f, 0.f, 0.f, 0.f, 0.f};
  float vyPrev = 0.f;
#pragma unroll
  for (int dy = 0; dy < 10; ++dy) {
    const int cur = dy & 1, prv = cur ^ 1;
    int iy = iyb + dy;
    float vy = (iy >= 0 && iy < H) ? 1.f : 0.f;
    const unsigned short* grow = gc + (size_t)(min(max(iy, 0), H - 1) * W) * 8;
    uint4 gv[4];
#pragma unroll
    for (int j = 0; j < 4; ++j) gv[j] = *(const uint4*)(grow + colOff[j] * 8);
#pragma unroll
    for (int j = 0; j < 3; ++j) {
      Hb[cur][j][0] = fmaf(ewx1[j], bflo(gv[j + 1].x), ewx0[j] * bflo(gv[j].x));
      Hb[cur][j][1] = fmaf(ewx1[j], bfhi(gv[j + 1].x), ewx0[j] * bfhi(gv[j].x));
      Hb[cur][j][2] = fmaf(ewx1[j], bflo(gv[j + 1].y), ewx0[j] * bflo(gv[j].y));
      Hb[cur][j][3] = fmaf(ewx1[j], bfhi(gv[j + 1].y), ewx0[j] * bfhi(gv[j].y));
      Hb[cur][j][4] = fmaf(ewx1[j], bflo(gv[j + 1].z), ewx0[j] * bflo(gv[j].z));
      Hb[cur][j][5] = fmaf(ewx1[j], bfhi(gv[j + 1].z), ewx0[j] * bfhi(gv[j].z));
      Hb[cur][j][6] = fmaf(ewx1[j], bflo(gv[j + 1].w), ewx0[j] * bflo(gv[j].w));
      Hb[cur][j][7] = fmaf(ewx1[j], bfhi(gv[j + 1].w), ewx0[j] * bfhi(gv[j].w));
    }
    if (dy >= 1) {
      const int dyk = dy - 1;
      float e0 = wy0 * vyPrev, e1 = wy1 * vy;
#pragma unroll
      for (int j = 0; j < 3; ++j) {
        float o[8];
#pragma unroll
        for (int e = 0; e < 8; ++e) {
          o[e] = fmaf(e0, Hb[prv][j][e], fmaf(e1, Hb[cur][j][e], av[e]));
          sum[e] += o[e];
          ssq[e] = fmaf(o[e], o[e], ssq[e]);
        }
        uint4 pk;
        pk.x = pkbf(o[0], o[1]);
        pk.y = pkbf(o[2], o[3]);
        pk.z = pkbf(o[4], o[5]);
        pk.w = pkbf(o[6], o[7]);
        int kk = (j0 + j) * 9 + dyk;   // k = xdisp*9 + ydisp (reference order)
        *(uint4*)(yb + (size_t)kk * 12 * P * 8) = pk;
      }
    }
    vyPrev = vy;
  }
#pragma unroll
  for (int m = 1; m < 64; m <<= 1) {
#pragma unroll
    for (int e = 0; e < 8; ++e) {
      sum[e] += __shfl_xor(sum[e], m);
      ssq[e] += __shfl_xor(ssq[e], m);
    }
  }
  if ((t & 63) == 0) {
    int slot = b & (NSLOT - 1);
#pragma unroll
    for (int e = 0; e < 8; ++e) {
      atomicAdd(&ws[S1SUM + slot * C1 + c8 * 8 + e], sum[e]);
      atomicAdd(&ws[S1SSQ + slot * C1 + c8 * 8 + e], ssq[e]);
    }
  }
}

__global__ void k_finalize(float* __restrict__ ws, int sumO, int ssqO,
                           const float* __restrict__ gamma, const float* __restrict__ beta,
                           int sO, int tO, int C) {
  int c = threadIdx.x;
  if (c < C) {
    float su = 0.f, sq = 0.f;
    for (int s = 0; s < NSLOT; ++s) { su += ws[sumO + s * C + c]; sq += ws[ssqO + s * C + c]; }
    float mean = su * (1.0f / (float)NS);
    float var = sq * (1.0f / (float)NS) - mean * mean;
    float sc = gamma[c] * rsqrtf(var + EPSF);
    ws[sO + c] = sc;
    ws[tO + c] = beta[c] - mean * sc;
  }
}

// Gram pass: x1 = bn1+relu(y1) -> G += x1^T x1 + m1 = sum(x1); atomics into 8 G-slots
// build mapping: c8 = t>>4 (active<12), pg = t&15 (8 px each), uint4 y1 loads
__global__ __launch_bounds__(256) void k_gram(const unsigned short* __restrict__ y1T,
                                              float* __restrict__ ws) {
  __shared__ unsigned short x1t[96 * X1TS];   // 26112B
  int t = threadIdx.x, b = blockIdx.x;
  int w = t >> 6, l = t & 63;
  int lr = l & 15, lh = l >> 4;
  int i0 = (w >> 1) * 48, j0 = (w & 1) * 48;  // each wave owns a 3x3 block of 16-tiles
  f32x4 acc[9];
  f32x4 zero4 = {0.f, 0.f, 0.f, 0.f};
#pragma unroll
  for (int q = 0; q < 9; ++q) acc[q] = zero4;
  int c8 = t >> 4, pg = t & 15;
  float s1v[8], t1v[8];
  if (c8 < 12) {
#pragma unroll
    for (int e = 0; e < 8; ++e) { s1v[e] = ws[S1Sc + c8 * 8 + e]; t1v[e] = ws[S1Tc + c8 * 8 + e]; }
  }
  float msum[8] = {0.f, 0.f, 0.f, 0.f, 0.f, 0.f, 0.f, 0.f};
  for (int it = 0; it < 16; ++it) {
    int idx = b * 16 + it;
    int k = idx >> 6, p0 = (idx & 63) << 7;
    const unsigned short* y1k = y1T + (size_t)k * P * 96;
    __syncthreads();   // previous iteration's Gram reads done
    if (c8 < 12) {
      int pbase = p0 + pg * 8;
      unsigned rowu[8][4];
#pragma unroll
      for (int ii = 0; ii < 8; ii += 2) {
        uint4 va = *(const uint4*)(y1k + ((size_t)c8 * P + pbase + ii) * 8);
        uint4 vb = *(const uint4*)(y1k + ((size_t)c8 * P + pbase + ii + 1) * 8);
        float xa[8], xb[8];
        xa[0] = fmaxf(0.f, fmaf(s1v[0], bflo(va.x), t1v[0]));
        xa[1] = fmaxf(0.f, fmaf(s1v[1], bfhi(va.x), t1v[1]));
        xa[2] = fmaxf(0.f, fmaf(s1v[2], bflo(va.y), t1v[2]));
        xa[3] = fmaxf(0.f, fmaf(s1v[3], bfhi(va.y), t1v[3]));
        xa[4] = fmaxf(0.f, fmaf(s1v[4], bflo(va.z), t1v[4]));
        xa[5] = fmaxf(0.f, fmaf(s1v[5], bfhi(va.z), t1v[5]));
        xa[6] = fmaxf(0.f, fmaf(s1v[6], bflo(va.w), t1v[6]));
        xa[7] = fmaxf(0.f, fmaf(s1v[7], bfhi(va.w), t1v[7]));
        xb[0] = fmaxf(0.f, fmaf(s1v[0], bflo(vb.x), t1v[0]));
        xb[1] = fmaxf(0.f, fmaf(s1v[1], bfhi(vb.x), t1v[1]));
        xb[2] = fmaxf(0.f, fmaf(s1v[2], bflo(vb.y), t1v[2]));
        xb[3] = fmaxf(0.f, fmaf(s1v[3], bfhi(vb.y), t1v[3]));
        xb[4] = fmaxf(0.f, fmaf(s1v[4], bflo(vb.z), t1v[4]));
        xb[5] = fmaxf(0.f, fmaf(s1v[5], bfhi(vb.z), t1v[5]));
        xb[6] = fmaxf(0.f, fmaf(s1v[6], bflo(vb.w), t1v[6]));
        xb[7] = fmaxf(0.f, fmaf(s1v[7], bfhi(vb.w), t1v[7]));
#pragma unroll
        for (int e = 0; e < 8; ++e) {
          msum[e] += xa[e] + xb[e];
          rowu[e][ii >> 1] = pkbf(xa[e], xb[e]);
        }
      }
#pragma unroll
      for (int e = 0; e < 8; ++e) {
        unsigned short* dst = x1t + (c8 * 8 + e) * X1TS + pg * 8;
        uint4 pk; pk.x = rowu[e][0]; pk.y = rowu[e][1]; pk.z = rowu[e][2]; pk.w = rowu[e][3];
        *(uint4*)dst = pk;
      }
    }
    __syncthreads();
#pragma unroll
    for (int kk = 0; kk < 4; ++kk) {
      bf16x8 a3[3], b3[3];
#pragma unroll
      for (int a = 0; a < 3; ++a)
        a3[a] = *(const bf16x8*)(const void*)(x1t + (i0 + a * 16 + lr) * X1TS + kk * 32 + lh * 8);
#pragma unroll
      for (int bb = 0; bb < 3; ++bb)
        b3[bb] = *(const bf16x8*)(const void*)(x1t + (j0 + bb * 16 + lr) * X1TS + kk * 32 + lh * 8);
#pragma unroll
      for (int a = 0; a < 3; ++a)
#pragma unroll
        for (int bb = 0; bb < 3; ++bb)
          acc[a * 3 + bb] = __builtin_amdgcn_mfma_f32_16x16x32_bf16(a3[a], b3[bb], acc[a * 3 + bb], 0, 0, 0);
    }
  }
  // accumulate partial G into L2-resident slot copies
  {
    float* gp = ws + GSLOT + (b & (NGSLOT - 1)) * 9216;
#pragma unroll
    for (int a = 0; a < 3; ++a)
#pragma unroll
      for (int bb = 0; bb < 3; ++bb) {
        int ti = (w >> 1) * 3 + a, tj = (w & 1) * 3 + bb;
        f32x4 v = acc[a * 3 + bb];
#pragma unroll
        for (int r = 0; r < 4; ++r)
          atomicAdd(&gp[(ti * 16 + lh * 4 + r) * 96 + tj * 16 + lr], v[r]);
      }
  }
  if (c8 < 12) {
#pragma unroll
    for (int m = 1; m < 16; m <<= 1)
#pragma unroll
      for (int e = 0; e < 8; ++e) msum[e] += __shfl_xor(msum[e], m);
    if (pg == 0) {
      int slot = b & (NSLOT - 1);
#pragma unroll
      for (int e = 0; e < 8; ++e) atomicAdd(&ws[M1SUM + slot * C1 + c8 * 8 + e], msum[e]);
    }
  }
}

// fold 8 G-slots -> GOFF
__global__ void k_greduce(float* __restrict__ ws) {
  int e = blockIdx.x * 256 + threadIdx.x;   // 36 blocks
  float s = 0.f;
#pragma unroll
  for (int g = 0; g < NGSLOT; ++g) s += ws[GSLOT + g * 9216 + e];
  ws[GOFF + e] = s;
}

// stats2 from Gram: mean_o = w2_o.m1/N; E[y2^2]_o = w2_o^T G w2_o / N
__global__ __launch_bounds__(256) void k_fin2g(float* __restrict__ ws,
                                               const unsigned short* __restrict__ w2bf,
                                               const float* __restrict__ g2,
                                               const float* __restrict__ be2) {
  __shared__ float wrow[96];
  __shared__ float m1f[96];
  __shared__ float red[8];
  int o = blockIdx.x, t = threadIdx.x;
  if (t < 96) {
    wrow[t] = bfu(w2bf[o * 96 + t]);
    float s = 0.f;
    for (int sl = 0; sl < NSLOT; ++sl) s += ws[M1SUM + sl * C1 + t];
    m1f[t] = s;
  }
  __syncthreads();
  float quad = 0.f;
  for (int e = t; e < 9216; e += 256) {
    int i = e / 96, j = e - i * 96;
    quad = fmaf(wrow[i] * wrow[j], ws[GOFF + e], quad);
  }
  float msm = (t < 96) ? wrow[t] * m1f[t] : 0.f;
#pragma unroll
  for (int m = 1; m < 64; m <<= 1) { quad += __shfl_xor(quad, m); msm += __shfl_xor(msm, m); }
  if ((t & 63) == 0) { red[t >> 6] = quad; red[4 + (t >> 6)] = msm; }
  __syncthreads();
  if (t == 0) {
    float q = red[0] + red[1] + red[2] + red[3];
    float mm = red[4] + red[5] + red[6] + red[7];
    float mean = mm * (1.0f / (float)NS);
    float var = q * (1.0f / (float)NS) - mean * mean;
    float sc = g2[o] * rsqrtf(var + EPSF);
    ws[S2Sc + o] = sc;
    ws[S2Tc + o] = be2[o] - mean * sc;
  }
}

// build x1 (bn1+relu of y1T [c8][p][8]) into [128][X1S] LDS tile; uint4 loads
__device__ __forceinline__ void build_x1(const unsigned short* __restrict__ y1k,
                                         const float* __restrict__ ws,
                                         unsigned short* lds, int p0, int t) {
  int s = t >> 1, hh = t & 1;
  int p = p0 + s;
  const float* s1p = ws + S1Sc;
  const float* t1p = ws + S1Tc;
  unsigned short* base = lds + s * X1S + hh * 48;
#pragma unroll
  for (int i = 0; i < 6; ++i) {
    int c8i = hh * 6 + i;
    uint4 v = *(const uint4*)(y1k + ((size_t)c8i * P + p) * 8);
    int cb = c8i * 8;
    float x0 = fmaxf(0.f, fmaf(s1p[cb + 0], bflo(v.x), t1p[cb + 0]));
    float x1 = fmaxf(0.f, fmaf(s1p[cb + 1], bfhi(v.x), t1p[cb + 1]));
    float x2 = fmaxf(0.f, fmaf(s1p[cb + 2], bflo(v.y), t1p[cb + 2]));
    float x3 = fmaxf(0.f, fmaf(s1p[cb + 3], bfhi(v.y), t1p[cb + 3]));
    float x4 = fmaxf(0.f, fmaf(s1p[cb + 4], bflo(v.z), t1p[cb + 4]));
    float x5 = fmaxf(0.f, fmaf(s1p[cb + 5], bfhi(v.z), t1p[cb + 5]));
    float x6 = fmaxf(0.f, fmaf(s1p[cb + 6], bflo(v.w), t1p[cb + 6]));
    float x7 = fmaxf(0.f, fmaf(s1p[cb + 7], bfhi(v.w), t1p[cb + 7]));
    uint4 pk;
    pk.x = pkbf(x0, x1); pk.y = pkbf(x2, x3); pk.z = pkbf(x4, x5); pk.w = pkbf(x6, x7);
    *(uint4*)(base + i * 8) = pk;
  }
}

// fused layers 2+3 (128-px blocks); XCD-swizzled block order
__global__ __launch_bounds__(256) void k_l23(const unsigned short* __restrict__ y1T,
                                             float* __restrict__ ws,
                                             const unsigned short* __restrict__ w2bf,
                                             const unsigned short* __restrict__ w3bf,
                                             unsigned short* __restrict__ y3T) {
  __shared__ unsigned short ldss[128 * X1S];
  int t = threadIdx.x;
  int b = (blockIdx.x & 7) * 648 + (blockIdx.x >> 3);
  int k = b >> 6, p0 = (b & 63) << 7;
  size_t n0 = (size_t)k * P + p0;
  int slot = b & (NSLOT - 1);
  const unsigned short* y1k = y1T + (size_t)k * P * 96;
  build_x1(y1k, ws, ldss, p0, t);
  __syncthreads();
  int l = t & 63, wv = t >> 6;
  int o0w = wv * 32;
  int lr = l & 15, lh = l >> 4;
  bf16x8 af[2][3];
#pragma unroll
  for (int m = 0; m < 2; ++m)
#pragma unroll
    for (int kk = 0; kk < 3; ++kk)
      af[m][kk] = *(const bf16x8*)(const void*)(w2bf + (size_t)(o0w + m * 16 + lr) * 96 + kk * 32 + lh * 8);
  f32x4 acc[2][8];
  f32x4 zero4 = {0.f, 0.f, 0.f, 0.f};
#pragma unroll
  for (int m = 0; m < 2; ++m)
#pragma unroll
    for (int n = 0; n < 8; ++n) acc[m][n] = zero4;
#pragma unroll
  for (int kk = 0; kk < 3; ++kk)
#pragma unroll
    for (int n = 0; n < 8; ++n) {
      bf16x8 bfr = *(const bf16x8*)(const void*)(ldss + (n * 16 + lr) * X1S + kk * 32 + lh * 8);
      acc[0][n] = __builtin_amdgcn_mfma_f32_16x16x32_bf16(af[0][kk], bfr, acc[0][n], 0, 0, 0);
      acc[1][n] = __builtin_amdgcn_mfma_f32_16x16x32_bf16(af[1][kk], bfr, acc[1][n], 0, 0, 0);
    }
  float s2v[2][4], t2v[2][4];
#pragma unroll
  for (int m = 0; m < 2; ++m)
#pragma unroll
    for (int r = 0; r < 4; ++r) {
      int cc = o0w + m * 16 + lh * 4 + r;
      s2v[m][r] = ws[S2Sc + cc];
      t2v[m][r] = ws[S2Tc + cc];
    }
  int o2 = wv * 16;
  int ch4 = wv * 4 + lh;   // y3T chunk this lane writes
  bf16x8 af2[4];
#pragma unroll
  for (int kk = 0; kk < 4; ++kk)
    af2[kk] = *(const bf16x8*)(const void*)(w3bf + (size_t)(o2 + lr) * 128 + kk * 32 + lh * 8);
  unsigned short* x2s = ldss;               // [64][X2S] = 17408B (aliases x1)
  float ssum[4] = {0.f, 0.f, 0.f, 0.f}, sssq[4] = {0.f, 0.f, 0.f, 0.f};
#pragma unroll
  for (int h = 0; h < 2; ++h) {
    __syncthreads();   // h0: MFMA1 x1-reads done; h1: MFMA2(h0) x2-reads done
#pragma unroll
    for (int m = 0; m < 2; ++m)
#pragma unroll
      for (int n2 = 0; n2 < 4; ++n2) {
        f32x4 v = acc[m][h * 4 + n2];
        float x0 = fmaxf(0.f, fmaf(s2v[m][0], v[0], t2v[m][0]));
        float x1v = fmaxf(0.f, fmaf(s2v[m][1], v[1], t2v[m][1]));
        float x2v = fmaxf(0.f, fmaf(s2v[m][2], v[2], t2v[m][2]));
        float x3 = fmaxf(0.f, fmaf(s2v[m][3], v[3], t2v[m][3]));
        uint2 pk;
        pk.x = pkbf(x0, x1v);
        pk.y = pkbf(x2v, x3);
        *(uint2*)(x2s + (n2 * 16 + lr) * X2S + o0w + m * 16 + lh * 4) = pk;
      }
    __syncthreads();
    f32x4 acc2[4];
#pragma unroll
    for (int n2 = 0; n2 < 4; ++n2) acc2[n2] = zero4;
#pragma unroll
    for (int kk = 0; kk < 4; ++kk)
#pragma unroll
      for (int n2 = 0; n2 < 4; ++n2) {
        bf16x8 bfr = *(const bf16x8*)(const void*)(x2s + (n2 * 16 + lr) * X2S + kk * 32 + lh * 8);
        acc2[n2] = __builtin_amdgcn_mfma_f32_16x16x32_bf16(af2[kk], bfr, acc2[n2], 0, 0, 0);
      }
    // stats3 + direct transposed store
#pragma unroll
    for (int n2 = 0; n2 < 4; ++n2) {
      f32x4 v = acc2[n2];
#pragma unroll
      for (int r = 0; r < 4; ++r) { float x = v[r]; ssum[r] += x; sssq[r] = fmaf(x, x, sssq[r]); }
      uint2 pk;
      pk.x = pkbf(v[0], v[1]);
      pk.y = pkbf(v[2], v[3]);
      size_t n = n0 + h * 64 + n2 * 16 + lr;
      *(uint2*)(y3T + ((size_t)ch4 * NS + n) * 4) = pk;
    }
  }
#pragma unroll
  for (int msk = 1; msk < 16; msk <<= 1)
#pragma unroll
    for (int i = 0; i < 4; ++i) { ssum[i] += __shfl_xor(ssum[i], msk); sssq[i] += __shfl_xor(sssq[i], msk); }
  if (lr == 0) {
#pragma unroll
    for (int r = 0; r < 4; ++r) {
      int o = o2 + lh * 4 + r;
      atomicAdd(&ws[S3SUM + slot * C3 + o], ssum[r]);
      atomicAdd(&ws[S3SSQ + slot * C3 + o], sssq[r]);
    }
  }
}

// layer4: cost = w4 . relu(bn3(y3T)) + b4
__global__ __launch_bounds__(256) void k_layer4(const unsigned short* __restrict__ y3T,
                                                float* __restrict__ ws,
                                                const float* __restrict__ w4,
                                                const float* __restrict__ b4) {
  size_t n = (size_t)blockIdx.x * 256 + threadIdx.x;
  const float* s3p = ws + S3Sc;
  const float* t3p = ws + S3Tc;
  float acc = 0.f;
#pragma unroll
  for (int c16 = 0; c16 < 16; ++c16) {
    uint2 v = *(const uint2*)(y3T + ((size_t)c16 * NS + n) * 4);
    int c = c16 * 4;
    acc += fmaxf(0.f, fmaf(s3p[c + 0], bflo(v.x), t3p[c + 0])) * w4[c + 0];
    acc += fmaxf(0.f, fmaf(s3p[c + 1], bfhi(v.x), t3p[c + 1])) * w4[c + 1];
    acc += fmaxf(0.f, fmaf(s3p[c + 2], bflo(v.y), t3p[c + 2])) * w4[c + 2];
    acc += fmaxf(0.f, fmaf(s3p[c + 3], bfhi(v.y), t3p[c + 3])) * w4[c + 3];
  }
  ws[COST_OFF + n] = acc + b4[0];
}

// DAP
__global__ __launch_bounds__(256) void k_dap(const float* __restrict__ ws,
                                             const float* __restrict__ wdap,
                                             float* __restrict__ out) {
  __shared__ float wd[DD * DD];
  int t = threadIdx.x;
  for (int i = t; i < DD * DD; i += 256) wd[i] = wdap[i];
  __syncthreads();
  int p = blockIdx.x * 32 + (t & 31);
  int lg = t >> 5;
  const float* cost = ws + COST_OFF;
  float cr[81];
#pragma unroll
  for (int kk = 0; kk < 81; ++kk) cr[kk] = cost[kk * P + p];
  for (int l = lg; l < 81; l += 8) {
    float acc = 0.f;
#pragma unroll
    for (int kk = 0; kk < 81; ++kk) acc = fmaf(wd[l * 81 + kk], cr[kk], acc);
    out[(size_t)l * P + p] = acc;
  }
}

__global__ void k_marker(float* out) { out[0] = 1.0e30f; }

extern "C" void kernel_launch(void* const* d_in, const int* in_sizes, int n_in,
                              void* d_out, int out_size, void* d_ws, size_t ws_size,
                              hipStream_t stream) {
  const float* f1 = (const float*)d_in[0];
  const float* f2 = (const float*)d_in[1];
  const float* coords = (const float*)d_in[2];
  const float* w1 = (const float*)d_in[3];
  const float* g1 = (const float*)d_in[4];
  const float* be1 = (const float*)d_in[5];
  const float* w2 = (const float*)d_in[6];
  const float* g2 = (const float*)d_in[7];
  const float* be2 = (const float*)d_in[8];
  const float* w3 = (const float*)d_in[9];
  const float* g3 = (const float*)d_in[10];
  const float* be3 = (const float*)d_in[11];
  const float* w4 = (const float*)d_in[12];
  const float* b4 = (const float*)d_in[13];
  const float* wdap = (const float*)d_in[14];
  float* out = (float*)d_out;
  float* ws = (float*)d_ws;

  if (ws_size < WS_NEEDED) {
    k_marker<<<1, 1, 0, stream>>>(out);
    return;
  }
  unsigned short* aT = (unsigned short*)((char*)d_ws + A_BYTE);
  unsigned short* gT = (unsigned short*)((char*)d_ws + G_BYTE);
  unsigned short* w2bf = (unsigned short*)((char*)d_ws + W2BF_BYTE);
  unsigned short* w3bf = (unsigned short*)((char*)d_ws + W3BF_BYTE);
  unsigned short* y1T = (unsigned short*)((char*)d_ws + Y1_BYTE);
  unsigned short* y3T = (unsigned short*)((char*)d_ws + Y3_BYTE);

  hipMemsetAsync(d_ws, 0, (size_t)STATS_ZERO_FLOATS * 4, stream);
  k_prep<<<128, 256, 0, stream>>>(f1, f2, w1, aT, gT);
  k_wprep<<<80, 256, 0, stream>>>(w2, w3, w2bf, w3bf);
  k_sample<<<1152, 256, 0, stream>>>(coords, ws, aT, gT, y1T);
  k_finalize<<<1, 128, 0, stream>>>(ws, S1SUM, S1SSQ, g1, be1, S1Sc, S1Tc, C1);
  k_gram<<<NGB, 256, 0, stream>>>(y1T, ws);
  k_greduce<<<36, 256, 0, stream>>>(ws);
  k_fin2g<<<128, 256, 0, stream>>>(ws, w2bf, g2, be2);
  k_l23<<<5184, 256, 0, stream>>>(y1T, ws, w2bf, w3bf, y3T);
  k_finalize<<<1, 128, 0, stream>>>(ws, S3SUM, S3SSQ, g3, be3, S3Sc, S3Tc, C3);
  k_layer4<<<2592, 256, 0, stream>>>(y3T, ws, w4, b4);
  k_dap<<<256, 256, 0, stream>>>(ws, wdap, out);
}

// Round 18
// 278.719 us; speedup vs baseline: 1.0384x; 1.0370x over previous
//
#include <hip/hip_runtime.h>
#include <hip/hip_bf16.h>

#define H 64
#define W 128
#define P 8192        // H*W
#define DD 81
#define NS 663552     // DD*P
#define C1 96
#define C2 128
#define C3 64
#define EPSF 1e-5f
#define NSLOT 128

// LDS row strides in shorts (odd multiples of 8 shorts = odd x 16B -> even bank phases)
#define X1S 104       // 208B = 13*16B
#define X2S 136       // 272B = 17*16B
#define X1TS 136      // gram transposed tile stride

#define NGB 324       // gram blocks (x16 tiles) -- 1296x4 WORSE (r11: 4x G-atomics)
#define NGSLOT 8
// r13: l23 64-px tile & dap4 fusion regressed. r14: 3-way 4ch split neutral.
// r15: XCD swizzle neutral (kept). r16: launch consolidation negative (reverted).
// r17: [c8][p][8] layout: l23 -4.6us but sample +10us (VGPR/occupancy) -> reverted;
//      kept ONLY the l23 16B-read idea via pixel-pair uint4 loads on [c4][p][4] (r18).

typedef __attribute__((ext_vector_type(8))) short bf16x8;
typedef __attribute__((ext_vector_type(4))) float f32x4;

// ---- workspace layout (floats) ----
#define S1SUM 0                                  // 128*96
#define S1SSQ (S1SUM + NSLOT * C1)               // 12288
#define M1SUM (S1SSQ + NSLOT * C1)               // 24576, 128*96
#define S3SUM (M1SUM + NSLOT * C1)               // 36864, 128*64
#define S3SSQ (S3SUM + NSLOT * C3)               // 45056
#define GSLOT (S3SSQ + NSLOT * C3)               // 53248, 8*9216
#define STATS_ZERO_FLOATS (GSLOT + NGSLOT * 9216)  // 126976
#define S1Sc 126976
#define S1Tc (S1Sc + C1)
#define S2Sc (S1Tc + C1)
#define S2Tc (S2Sc + C2)
#define S3Sc (S2Tc + C2)
#define S3Tc (S3Sc + C3)
#define GOFF 127552                              // 9216 reduced Gram
#define COST_OFF (GOFF + 9216)                   // 136768
#define FLOAT_END (COST_OFF + NS)                // 800320
// byte-indexed region. aT/gT/y1T/y3T transposed: [chunk of 4ch][sample][4]
#define A_BYTE   ((size_t)FLOAT_END * 4)
#define G_BYTE   (A_BYTE + (size_t)P * 96 * 2)
#define W2BF_BYTE (G_BYTE + (size_t)P * 96 * 2)
#define W3BF_BYTE (W2BF_BYTE + (size_t)C2 * C1 * 2)
#define Y1_BYTE  (W3BF_BYTE + (size_t)C3 * C2 * 2)
#define Y3_BYTE  (Y1_BYTE + (size_t)NS * C1 * 2)
#define WS_NEEDED (Y3_BYTE + (size_t)NS * C3 * 2)

__device__ __forceinline__ float bflo(unsigned u) { return __uint_as_float(u << 16); }
__device__ __forceinline__ float bfhi(unsigned u) { return __uint_as_float(u & 0xffff0000u); }
__device__ __forceinline__ float bfu(unsigned short v) { return __uint_as_float((unsigned)v << 16); }

__device__ __forceinline__ unsigned pkbf(float a, float b) {
  __hip_bfloat162 h = __float22bfloat162_rn(make_float2(a, b));
  unsigned u; __builtin_memcpy(&u, &h, 4);
  return u;
}

// a = w1[:, :128] @ f1, g = w1[:, 128:] @ f2  -> bf16, transposed [c4][p][4]
__global__ __launch_bounds__(256) void k_prep(const float* __restrict__ f1,
                                              const float* __restrict__ f2,
                                              const float* __restrict__ w1,
                                              unsigned short* __restrict__ aT,
                                              unsigned short* __restrict__ gT) {
  __shared__ float tile[128][64];
  int t = threadIdx.x;
  int p0 = blockIdx.x * 64;
  int px = t & 63, q = t >> 6;
  int c0 = q * 24;
  for (int pass = 0; pass < 2; ++pass) {
    const float* src = pass ? f2 : f1;
    unsigned short* dst = pass ? gT : aT;
    int koff = pass ? 128 : 0;
    __syncthreads();
    for (int idx = t; idx < 8192; idx += 256) {
      int kk = idx >> 6, xx = idx & 63;
      tile[kk][xx] = src[kk * P + p0 + xx];
    }
    __syncthreads();
    float acc[24];
#pragma unroll
    for (int i = 0; i < 24; ++i) acc[i] = 0.f;
    for (int kk = 0; kk < 128; ++kk) {
      float fv = tile[kk][px];
#pragma unroll
      for (int i = 0; i < 24; ++i)
        acc[i] += w1[(c0 + i) * 256 + koff + kk] * fv;
    }
#pragma unroll
    for (int i = 0; i < 24; i += 4) {
      uint2 pk;
      pk.x = pkbf(acc[i + 0], acc[i + 1]);
      pk.y = pkbf(acc[i + 2], acc[i + 3]);
      *(uint2*)(dst + ((size_t)((c0 + i) >> 2) * P + p0 + px) * 4) = pk;
    }
  }
}

__global__ void k_wprep(const float* __restrict__ w2, const float* __restrict__ w3,
                        unsigned short* __restrict__ w2bf, unsigned short* __restrict__ w3bf) {
  int idx = blockIdx.x * 256 + threadIdx.x;
  if (idx < C2 * C1) {
    w2bf[idx] = (unsigned short)(pkbf(w2[idx], 0.f) & 0xffffu);
  } else if (idx < C2 * C1 + C3 * C2) {
    w3bf[idx - C2 * C1] = (unsigned short)(pkbf(w3[idx - C2 * C1], 0.f) & 0xffffu);
  }
}

// separable gather, split by x-displacement halves (r12-proven best)
__global__ __launch_bounds__(256) void k_sample(const float* __restrict__ coords,
                                                float* __restrict__ ws,
                                                const unsigned short* __restrict__ aT,
                                                const unsigned short* __restrict__ gT,
                                                unsigned short* __restrict__ y1T) {
  int t = threadIdx.x, b = blockIdx.x;
  int sub = b % 12;
  int ptile = b / 12;
  int cg = sub >> 1, jh = sub & 1;
  int j0 = jh * 5;
  int nj = 5 - jh;             // valid j count (wave-uniform)
  int c = cg * 4 + (t >> 6);   // chunk 0..23, uniform per wave
  int px = t & 63;
  int p = ptile * 64 + px;
  float cx = coords[p], cy = coords[P + p];
  float fx0 = floorf(cx), fy0 = floorf(cy);
  float wx1 = cx - fx0, wx0 = 1.f - wx1;
  float wy1 = cy - fy0, wy0 = 1.f - wy1;
  int ixb = (int)fx0 - 4 + j0, iyb = (int)fy0 - 4;
  int colOff[6];
  float vxv[6];
#pragma unroll
  for (int j = 0; j < 6; ++j) {
    int ix = ixb + j;
    vxv[j] = (ix >= 0 && ix < W) ? 1.f : 0.f;
    colOff[j] = min(max(ix, 0), W - 1);
  }
  float ewx0[5], ewx1[5];
#pragma unroll
  for (int j = 0; j < 5; ++j) { ewx0[j] = wx0 * vxv[j]; ewx1[j] = wx1 * vxv[j + 1]; }
  float av[4];
  {
    uint2 a2 = *(const uint2*)(aT + ((size_t)c * P + p) * 4);
    av[0] = bflo(a2.x); av[1] = bfhi(a2.x); av[2] = bflo(a2.y); av[3] = bfhi(a2.y);
  }
  const unsigned short* gc = gT + (size_t)c * P * 4;
  unsigned short* yb = y1T + ((size_t)c * P + p) * 4;
  float Hb[2][5][4];
  float sum[4] = {0.f, 0.f, 0.f, 0.f}, ssq[4] = {0.f, 0.f, 0.f, 0.f};
  float vyPrev = 0.f;
#pragma unroll
  for (int dy = 0; dy < 10; ++dy) {
    const int cur = dy & 1, prv = cur ^ 1;
    int iy = iyb + dy;
    float vy = (iy >= 0 && iy < H) ? 1.f : 0.f;
    const unsigned short* grow = gc + (size_t)(min(max(iy, 0), H - 1) * W) * 4;
    uint2 gv[6];
#pragma unroll
    for (int j = 0; j < 6; ++j) gv[j] = *(const uint2*)(grow + colOff[j] * 4);
#pragma unroll
    for (int j = 0; j < 5; ++j) {
      Hb[cur][j][0] = fmaf(ewx1[j], bflo(gv[j + 1].x), ewx0[j] * bflo(gv[j].x));
      Hb[cur][j][1] = fmaf(ewx1[j], bfhi(gv[j + 1].x), ewx0[j] * bfhi(gv[j].x));
      Hb[cur][j][2] = fmaf(ewx1[j], bflo(gv[j + 1].y), ewx0[j] * bflo(gv[j].y));
      Hb[cur][j][3] = fmaf(ewx1[j], bfhi(gv[j + 1].y), ewx0[j] * bfhi(gv[j].y));
    }
    if (dy >= 1) {
      const int dyk = dy - 1;
      float e0 = wy0 * vyPrev, e1 = wy1 * vy;
#pragma unroll
      for (int j = 0; j < 5; ++j) {
        if (j < nj) {   // wave-uniform guard (jh=1 has 4 valid j)
          float o0 = fmaf(e0, Hb[prv][j][0], fmaf(e1, Hb[cur][j][0], av[0]));
          float o1 = fmaf(e0, Hb[prv][j][1], fmaf(e1, Hb[cur][j][1], av[1]));
          float o2 = fmaf(e0, Hb[prv][j][2], fmaf(e1, Hb[cur][j][2], av[2]));
          float o3 = fmaf(e0, Hb[prv][j][3], fmaf(e1, Hb[cur][j][3], av[3]));
          sum[0] += o0; ssq[0] = fmaf(o0, o0, ssq[0]);
          sum[1] += o1; ssq[1] = fmaf(o1, o1, ssq[1]);
          sum[2] += o2; ssq[2] = fmaf(o2, o2, ssq[2]);
          sum[3] += o3; ssq[3] = fmaf(o3, o3, ssq[3]);
          uint2 pk;
          pk.x = pkbf(o0, o1);
          pk.y = pkbf(o2, o3);
          int kk = (j0 + j) * 9 + dyk;   // k = xdisp*9 + ydisp (reference order)
          *(uint2*)(yb + (size_t)kk * 24 * P * 4) = pk;
        }
      }
    }
    vyPrev = vy;
  }
#pragma unroll
  for (int m = 1; m < 64; m <<= 1) {
#pragma unroll
    for (int e = 0; e < 4; ++e) {
      sum[e] += __shfl_xor(sum[e], m);
      ssq[e] += __shfl_xor(ssq[e], m);
    }
  }
  if ((t & 63) == 0) {
    int slot = b & (NSLOT - 1);
#pragma unroll
    for (int e = 0; e < 4; ++e) {
      atomicAdd(&ws[S1SUM + slot * C1 + c * 4 + e], sum[e]);
      atomicAdd(&ws[S1SSQ + slot * C1 + c * 4 + e], ssq[e]);
    }
  }
}

__global__ void k_finalize(float* __restrict__ ws, int sumO, int ssqO,
                           const float* __restrict__ gamma, const float* __restrict__ beta,
                           int sO, int tO, int C) {
  int c = threadIdx.x;
  if (c < C) {
    float su = 0.f, sq = 0.f;
    for (int s = 0; s < NSLOT; ++s) { su += ws[sumO + s * C + c]; sq += ws[ssqO + s * C + c]; }
    float mean = su * (1.0f / (float)NS);
    float var = sq * (1.0f / (float)NS) - mean * mean;
    float sc = gamma[c] * rsqrtf(var + EPSF);
    ws[sO + c] = sc;
    ws[tO + c] = beta[c] - mean * sc;
  }
}

// Gram pass: x1 = bn1+relu(y1) -> G += x1^T x1 + m1 = sum(x1); atomics into 8 G-slots
__global__ __launch_bounds__(256) void k_gram(const unsigned short* __restrict__ y1T,
                                              float* __restrict__ ws) {
  __shared__ unsigned short x1t[96 * X1TS];   // 26112B
  int t = threadIdx.x, b = blockIdx.x;
  int w = t >> 6, l = t & 63;
  int lr = l & 15, lh = l >> 4;
  int i0 = (w >> 1) * 48, j0 = (w & 1) * 48;  // each wave owns a 3x3 block of 16-tiles
  f32x4 acc[9];
  f32x4 zero4 = {0.f, 0.f, 0.f, 0.f};
#pragma unroll
  for (int q = 0; q < 9; ++q) acc[q] = zero4;
  int c = t >> 3, pg = t & 7;   // build mapping: chunk c (0..23 active), pixel group pg
  float s1v[4], t1v[4];
  if (c < 24) {
#pragma unroll
    for (int e = 0; e < 4; ++e) { s1v[e] = ws[S1Sc + c * 4 + e]; t1v[e] = ws[S1Tc + c * 4 + e]; }
  }
  float msum[4] = {0.f, 0.f, 0.f, 0.f};
  for (int it = 0; it < 16; ++it) {
    int idx = b * 16 + it;
    int k = idx >> 6, p0 = (idx & 63) << 7;
    const unsigned short* y1k = y1T + (size_t)k * P * 96;
    __syncthreads();   // previous iteration's Gram reads done
    if (c < 24) {
      int pbase = p0 + pg * 16;
      unsigned rowu[4][8];
#pragma unroll
      for (int ii = 0; ii < 8; ++ii) {
        uint4 v = *(const uint4*)(y1k + ((size_t)c * P + pbase + ii * 2) * 4);
        float x00 = fmaxf(0.f, fmaf(s1v[0], bflo(v.x), t1v[0]));
        float x10 = fmaxf(0.f, fmaf(s1v[1], bfhi(v.x), t1v[1]));
        float x20 = fmaxf(0.f, fmaf(s1v[2], bflo(v.y), t1v[2]));
        float x30 = fmaxf(0.f, fmaf(s1v[3], bfhi(v.y), t1v[3]));
        float x01 = fmaxf(0.f, fmaf(s1v[0], bflo(v.z), t1v[0]));
        float x11 = fmaxf(0.f, fmaf(s1v[1], bfhi(v.z), t1v[1]));
        float x21 = fmaxf(0.f, fmaf(s1v[2], bflo(v.w), t1v[2]));
        float x31 = fmaxf(0.f, fmaf(s1v[3], bfhi(v.w), t1v[3]));
        msum[0] += x00 + x01; msum[1] += x10 + x11;
        msum[2] += x20 + x21; msum[3] += x30 + x31;
        rowu[0][ii] = pkbf(x00, x01);
        rowu[1][ii] = pkbf(x10, x11);
        rowu[2][ii] = pkbf(x20, x21);
        rowu[3][ii] = pkbf(x30, x31);
      }
#pragma unroll
      for (int e = 0; e < 4; ++e) {
        unsigned short* dst = x1t + (c * 4 + e) * X1TS + pg * 16;
        uint4 pk0; pk0.x = rowu[e][0]; pk0.y = rowu[e][1]; pk0.z = rowu[e][2]; pk0.w = rowu[e][3];
        uint4 pk1; pk1.x = rowu[e][4]; pk1.y = rowu[e][5]; pk1.z = rowu[e][6]; pk1.w = rowu[e][7];
        *(uint4*)dst = pk0;
        *(uint4*)(dst + 8) = pk1;
      }
    }
    __syncthreads();
#pragma unroll
    for (int kk = 0; kk < 4; ++kk) {
      bf16x8 a3[3], b3[3];
#pragma unroll
      for (int a = 0; a < 3; ++a)
        a3[a] = *(const bf16x8*)(const void*)(x1t + (i0 + a * 16 + lr) * X1TS + kk * 32 + lh * 8);
#pragma unroll
      for (int bb = 0; bb < 3; ++bb)
        b3[bb] = *(const bf16x8*)(const void*)(x1t + (j0 + bb * 16 + lr) * X1TS + kk * 32 + lh * 8);
#pragma unroll
      for (int a = 0; a < 3; ++a)
#pragma unroll
        for (int bb = 0; bb < 3; ++bb)
          acc[a * 3 + bb] = __builtin_amdgcn_mfma_f32_16x16x32_bf16(a3[a], b3[bb], acc[a * 3 + bb], 0, 0, 0);
    }
  }
  // accumulate partial G into L2-resident slot copies
  {
    float* gp = ws + GSLOT + (b & (NGSLOT - 1)) * 9216;
#pragma unroll
    for (int a = 0; a < 3; ++a)
#pragma unroll
      for (int bb = 0; bb < 3; ++bb) {
        int ti = (w >> 1) * 3 + a, tj = (w & 1) * 3 + bb;
        f32x4 v = acc[a * 3 + bb];
#pragma unroll
        for (int r = 0; r < 4; ++r)
          atomicAdd(&gp[(ti * 16 + lh * 4 + r) * 96 + tj * 16 + lr], v[r]);
      }
  }
  if (c < 24) {
#pragma unroll
    for (int m = 1; m < 8; m <<= 1)
#pragma unroll
      for (int e = 0; e < 4; ++e) msum[e] += __shfl_xor(msum[e], m);
    if (pg == 0) {
      int slot = b & (NSLOT - 1);
#pragma unroll
      for (int e = 0; e < 4; ++e) atomicAdd(&ws[M1SUM + slot * C1 + c * 4 + e], msum[e]);
    }
  }
}

// fold 8 G-slots -> GOFF
__global__ void k_greduce(float* __restrict__ ws) {
  int e = blockIdx.x * 256 + threadIdx.x;   // 36 blocks
  float s = 0.f;
#pragma unroll
  for (int g = 0; g < NGSLOT; ++g) s += ws[GSLOT + g * 9216 + e];
  ws[GOFF + e] = s;
}

// stats2 from Gram: mean_o = w2_o.m1/N; E[y2^2]_o = w2_o^T G w2_o / N
__global__ __launch_bounds__(256) void k_fin2g(float* __restrict__ ws,
                                               const unsigned short* __restrict__ w2bf,
                                               const float* __restrict__ g2,
                                               const float* __restrict__ be2) {
  __shared__ float wrow[96];
  __shared__ float m1f[96];
  __shared__ float red[8];
  int o = blockIdx.x, t = threadIdx.x;
  if (t < 96) {
    wrow[t] = bfu(w2bf[o * 96 + t]);
    float s = 0.f;
    for (int sl = 0; sl < NSLOT; ++sl) s += ws[M1SUM + sl * C1 + t];
    m1f[t] = s;
  }
  __syncthreads();
  float quad = 0.f;
  for (int e = t; e < 9216; e += 256) {
    int i = e / 96, j = e - i * 96;
    quad = fmaf(wrow[i] * wrow[j], ws[GOFF + e], quad);
  }
  float msm = (t < 96) ? wrow[t] * m1f[t] : 0.f;
#pragma unroll
  for (int m = 1; m < 64; m <<= 1) { quad += __shfl_xor(quad, m); msm += __shfl_xor(msm, m); }
  if ((t & 63) == 0) { red[t >> 6] = quad; red[4 + (t >> 6)] = msm; }
  __syncthreads();
  if (t == 0) {
    float q = red[0] + red[1] + red[2] + red[3];
    float mm = red[4] + red[5] + red[6] + red[7];
    float mean = mm * (1.0f / (float)NS);
    float var = q * (1.0f / (float)NS) - mean * mean;
    float sc = g2[o] * rsqrtf(var + EPSF);
    ws[S2Sc + o] = sc;
    ws[S2Tc + o] = be2[o] - mean * sc;
  }
}

// build x1 (bn1+relu of y1T) into [128][X1S] LDS tile; PIXEL-PAIR uint4 loads (r18)
// thread (sp = t>>2, q = t&3): loads pixels {2sp, 2sp+1} x 4ch for 6 chunks q*6+i
__device__ __forceinline__ void build_x1(const unsigned short* __restrict__ y1k,
                                         const float* __restrict__ ws,
                                         unsigned short* lds, int p0, int t) {
  int sp = t >> 2, q = t & 3;
  int p = p0 + sp * 2;
  const float* s1p = ws + S1Sc;
  const float* t1p = ws + S1Tc;
  unsigned short* b0 = lds + (sp * 2) * X1S;
  unsigned short* b1 = lds + (sp * 2 + 1) * X1S;
#pragma unroll
  for (int i = 0; i < 6; ++i) {
    int c4i = q * 6 + i;
    uint4 v = *(const uint4*)(y1k + ((size_t)c4i * P + p) * 4);  // px pair x 4ch, 16B
    int cb = c4i * 4;
    float x0 = fmaxf(0.f, fmaf(s1p[cb + 0], bflo(v.x), t1p[cb + 0]));
    float x1 = fmaxf(0.f, fmaf(s1p[cb + 1], bfhi(v.x), t1p[cb + 1]));
    float x2 = fmaxf(0.f, fmaf(s1p[cb + 2], bflo(v.y), t1p[cb + 2]));
    float x3 = fmaxf(0.f, fmaf(s1p[cb + 3], bfhi(v.y), t1p[cb + 3]));
    float y0 = fmaxf(0.f, fmaf(s1p[cb + 0], bflo(v.z), t1p[cb + 0]));
    float y1v = fmaxf(0.f, fmaf(s1p[cb + 1], bfhi(v.z), t1p[cb + 1]));
    float y2 = fmaxf(0.f, fmaf(s1p[cb + 2], bflo(v.w), t1p[cb + 2]));
    float y3v = fmaxf(0.f, fmaf(s1p[cb + 3], bfhi(v.w), t1p[cb + 3]));
    uint2 pa; pa.x = pkbf(x0, x1); pa.y = pkbf(x2, x3);
    uint2 pb; pb.x = pkbf(y0, y1v); pb.y = pkbf(y2, y3v);
    *(uint2*)(b0 + cb) = pa;
    *(uint2*)(b1 + cb) = pb;
  }
}

// fused layers 2+3 (128-px blocks); XCD-swizzled block order
__global__ __launch_bounds__(256) void k_l23(const unsigned short* __restrict__ y1T,
                                             float* __restrict__ ws,
                                             const unsigned short* __restrict__ w2bf,
                                             const unsigned short* __restrict__ w3bf,
                                             unsigned short* __restrict__ y3T) {
  __shared__ unsigned short ldss[128 * X1S];
  int t = threadIdx.x;
  int b = (blockIdx.x & 7) * 648 + (blockIdx.x >> 3);
  int k = b >> 6, p0 = (b & 63) << 7;
  size_t n0 = (size_t)k * P + p0;
  int slot = b & (NSLOT - 1);
  const unsigned short* y1k = y1T + (size_t)k * P * 96;
  build_x1(y1k, ws, ldss, p0, t);
  __syncthreads();
  int l = t & 63, wv = t >> 6;
  int o0w = wv * 32;
  int lr = l & 15, lh = l >> 4;
  bf16x8 af[2][3];
#pragma unroll
  for (int m = 0; m < 2; ++m)
#pragma unroll
    for (int kk = 0; kk < 3; ++kk)
      af[m][kk] = *(const bf16x8*)(const void*)(w2bf + (size_t)(o0w + m * 16 + lr) * 96 + kk * 32 + lh * 8);
  f32x4 acc[2][8];
  f32x4 zero4 = {0.f, 0.f, 0.f, 0.f};
#pragma unroll
  for (int m = 0; m < 2; ++m)
#pragma unroll
    for (int n = 0; n < 8; ++n) acc[m][n] = zero4;
#pragma unroll
  for (int kk = 0; kk < 3; ++kk)
#pragma unroll
    for (int n = 0; n < 8; ++n) {
      bf16x8 bfr = *(const bf16x8*)(const void*)(ldss + (n * 16 + lr) * X1S + kk * 32 + lh * 8);
      acc[0][n] = __builtin_amdgcn_mfma_f32_16x16x32_bf16(af[0][kk], bfr, acc[0][n], 0, 0, 0);
      acc[1][n] = __builtin_amdgcn_mfma_f32_16x16x32_bf16(af[1][kk], bfr, acc[1][n], 0, 0, 0);
    }
  float s2v[2][4], t2v[2][4];
#pragma unroll
  for (int m = 0; m < 2; ++m)
#pragma unroll
    for (int r = 0; r < 4; ++r) {
      int cc = o0w + m * 16 + lh * 4 + r;
      s2v[m][r] = ws[S2Sc + cc];
      t2v[m][r] = ws[S2Tc + cc];
    }
  int o2 = wv * 16;
  int ch4 = wv * 4 + lh;   // y3T chunk this lane writes
  bf16x8 af2[4];
#pragma unroll
  for (int kk = 0; kk < 4; ++kk)
    af2[kk] = *(const bf16x8*)(const void*)(w3bf + (size_t)(o2 + lr) * 128 + kk * 32 + lh * 8);
  unsigned short* x2s = ldss;               // [64][X2S] = 17408B (aliases x1)
  float ssum[4] = {0.f, 0.f, 0.f, 0.f}, sssq[4] = {0.f, 0.f, 0.f, 0.f};
#pragma unroll
  for (int h = 0; h < 2; ++h) {
    __syncthreads();   // h0: MFMA1 x1-reads done; h1: MFMA2(h0) x2-reads done
#pragma unroll
    for (int m = 0; m < 2; ++m)
#pragma unroll
      for (int n2 = 0; n2 < 4; ++n2) {
        f32x4 v = acc[m][h * 4 + n2];
        float x0 = fmaxf(0.f, fmaf(s2v[m][0], v[0], t2v[m][0]));
        float x1v = fmaxf(0.f, fmaf(s2v[m][1], v[1], t2v[m][1]));
        float x2v = fmaxf(0.f, fmaf(s2v[m][2], v[2], t2v[m][2]));
        float x3 = fmaxf(0.f, fmaf(s2v[m][3], v[3], t2v[m][3]));
        uint2 pk;
        pk.x = pkbf(x0, x1v);
        pk.y = pkbf(x2v, x3);
        *(uint2*)(x2s + (n2 * 16 + lr) * X2S + o0w + m * 16 + lh * 4) = pk;
      }
    __syncthreads();
    f32x4 acc2[4];
#pragma unroll
    for (int n2 = 0; n2 < 4; ++n2) acc2[n2] = zero4;
#pragma unroll
    for (int kk = 0; kk < 4; ++kk)
#pragma unroll
      for (int n2 = 0; n2 < 4; ++n2) {
        bf16x8 bfr = *(const bf16x8*)(const void*)(x2s + (n2 * 16 + lr) * X2S + kk * 32 + lh * 8);
        acc2[n2] = __builtin_amdgcn_mfma_f32_16x16x32_bf16(af2[kk], bfr, acc2[n2], 0, 0, 0);
      }
    // stats3 + direct transposed store
#pragma unroll
    for (int n2 = 0; n2 < 4; ++n2) {
      f32x4 v = acc2[n2];
#pragma unroll
      for (int r = 0; r < 4; ++r) { float x = v[r]; ssum[r] += x; sssq[r] = fmaf(x, x, sssq[r]); }
      uint2 pk;
      pk.x = pkbf(v[0], v[1]);
      pk.y = pkbf(v[2], v[3]);
      size_t n = n0 + h * 64 + n2 * 16 + lr;
      *(uint2*)(y3T + ((size_t)ch4 * NS + n) * 4) = pk;
    }
  }
#pragma unroll
  for (int msk = 1; msk < 16; msk <<= 1)
#pragma unroll
    for (int i = 0; i < 4; ++i) { ssum[i] += __shfl_xor(ssum[i], msk); sssq[i] += __shfl_xor(sssq[i], msk); }
  if (lr == 0) {
#pragma unroll
    for (int r = 0; r < 4; ++r) {
      int o = o2 + lh * 4 + r;
      atomicAdd(&ws[S3SUM + slot * C3 + o], ssum[r]);
      atomicAdd(&ws[S3SSQ + slot * C3 + o], sssq[r]);
    }
  }
}

// layer4: cost = w4 . relu(bn3(y3T)) + b4
__global__ __launch_bounds__(256) void k_layer4(const unsigned short* __restrict__ y3T,
                                                float* __restrict__ ws,
                                                const float* __restrict__ w4,
                                                const float* __restrict__ b4) {
  size_t n = (size_t)blockIdx.x * 256 + threadIdx.x;
  const float* s3p = ws + S3Sc;
  const float* t3p = ws + S3Tc;
  float acc = 0.f;
#pragma unroll
  for (int c16 = 0; c16 < 16; ++c16) {
    uint2 v = *(const uint2*)(y3T + ((size_t)c16 * NS + n) * 4);
    int c = c16 * 4;
    acc += fmaxf(0.f, fmaf(s3p[c + 0], bflo(v.x), t3p[c + 0])) * w4[c + 0];
    acc += fmaxf(0.f, fmaf(s3p[c + 1], bfhi(v.x), t3p[c + 1])) * w4[c + 1];
    acc += fmaxf(0.f, fmaf(s3p[c + 2], bflo(v.y), t3p[c + 2])) * w4[c + 2];
    acc += fmaxf(0.f, fmaf(s3p[c + 3], bfhi(v.y), t3p[c + 3])) * w4[c + 3];
  }
  ws[COST_OFF + n] = acc + b4[0];
}

// DAP
__global__ __launch_bounds__(256) void k_dap(const float* __restrict__ ws,
                                             const float* __restrict__ wdap,
                                             float* __restrict__ out) {
  __shared__ float wd[DD * DD];
  int t = threadIdx.x;
  for (int i = t; i < DD * DD; i += 256) wd[i] = wdap[i];
  __syncthreads();
  int p = blockIdx.x * 32 + (t & 31);
  int lg = t >> 5;
  const float* cost = ws + COST_OFF;
  float cr[81];
#pragma unroll
  for (int kk = 0; kk < 81; ++kk) cr[kk] = cost[kk * P + p];
  for (int l = lg; l < 81; l += 8) {
    float acc = 0.f;
#pragma unroll
    for (int kk = 0; kk < 81; ++kk) acc = fmaf(wd[l * 81 + kk], cr[kk], acc);
    out[(size_t)l * P + p] = acc;
  }
}

__global__ void k_marker(float* out) { out[0] = 1.0e30f; }

extern "C" void kernel_launch(void* const* d_in, const int* in_sizes, int n_in,
                              void* d_out, int out_size, void* d_ws, size_t ws_size,
                              hipStream_t stream) {
  const float* f1 = (const float*)d_in[0];
  const float* f2 = (const float*)d_in[1];
  const float* coords = (const float*)d_in[2];
  const float* w1 = (const float*)d_in[3];
  const float* g1 = (const float*)d_in[4];
  const float* be1 = (const float*)d_in[5];
  const float* w2 = (const float*)d_in[6];
  const float* g2 = (const float*)d_in[7];
  const float* be2 = (const float*)d_in[8];
  const float* w3 = (const float*)d_in[9];
  const float* g3 = (const float*)d_in[10];
  const float* be3 = (const float*)d_in[11];
  const float* w4 = (const float*)d_in[12];
  const float* b4 = (const float*)d_in[13];
  const float* wdap = (const float*)d_in[14];
  float* out = (float*)d_out;
  float* ws = (float*)d_ws;

  if (ws_size < WS_NEEDED) {
    k_marker<<<1, 1, 0, stream>>>(out);
    return;
  }
  unsigned short* aT = (unsigned short*)((char*)d_ws + A_BYTE);
  unsigned short* gT = (unsigned short*)((char*)d_ws + G_BYTE);
  unsigned short* w2bf = (unsigned short*)((char*)d_ws + W2BF_BYTE);
  unsigned short* w3bf = (unsigned short*)((char*)d_ws + W3BF_BYTE);
  unsigned short* y1T = (unsigned short*)((char*)d_ws + Y1_BYTE);
  unsigned short* y3T = (unsigned short*)((char*)d_ws + Y3_BYTE);

  hipMemsetAsync(d_ws, 0, (size_t)STATS_ZERO_FLOATS * 4, stream);
  k_prep<<<128, 256, 0, stream>>>(f1, f2, w1, aT, gT);
  k_wprep<<<80, 256, 0, stream>>>(w2, w3, w2bf, w3bf);
  k_sample<<<1536, 256, 0, stream>>>(coords, ws, aT, gT, y1T);
  k_finalize<<<1, 128, 0, stream>>>(ws, S1SUM, S1SSQ, g1, be1, S1Sc, S1Tc, C1);
  k_gram<<<NGB, 256, 0, stream>>>(y1T, ws);
  k_greduce<<<36, 256, 0, stream>>>(ws);
  k_fin2g<<<128, 256, 0, stream>>>(ws, w2bf, g2, be2);
  k_l23<<<5184, 256, 0, stream>>>(y1T, ws, w2bf, w3bf, y3T);
  k_finalize<<<1, 128, 0, stream>>>(ws, S3SUM, S3SSQ, g3, be3, S3Sc, S3Tc, C3);
  k_layer4<<<2592, 256, 0, stream>>>(y3T, ws, w4, b4);
  k_dap<<<256, 256, 0, stream>>>(ws, wdap, out);
}